// Round 4
// baseline (142.857 us; speedup 1.0000x reference)
//
#include <hip/hip_runtime.h>
#include <hip/hip_bf16.h>
#include <math.h>

#define S_ 64
#define B_ 128
#define H_ 768
#define A_ 768
#define NT 12            // K-steps: 768 / 64

typedef __bf16 bf16_t;
typedef __attribute__((ext_vector_type(8))) __bf16 bf16x8;
typedef __attribute__((ext_vector_type(4))) __bf16 bf16x4;
typedef __attribute__((ext_vector_type(4))) float f32x4;

__device__ __forceinline__ bf16x8 pack8(float4 a, float4 b) {
    bf16x8 o;
    o[0]=(bf16_t)a.x; o[1]=(bf16_t)a.y; o[2]=(bf16_t)a.z; o[3]=(bf16_t)a.w;
    o[4]=(bf16_t)b.x; o[5]=(bf16_t)b.y; o[6]=(bf16_t)b.z; o[7]=(bf16_t)b.w;
    return o;
}

// raw barrier: LDS drained, but outstanding global->reg loads stay in flight
__device__ __forceinline__ void barrier_keep_loads() {
    asm volatile("s_waitcnt lgkmcnt(0)" ::: "memory");
    __builtin_amdgcn_sched_barrier(0);
    __builtin_amdgcn_s_barrier();
    __builtin_amdgcn_sched_barrier(0);
}

// ============================================================================
// FAST PATH
// ============================================================================

// ---- prep: Wv [s][h][a] f32 -> WT [s][a][h] bf16 (s==64 slab = Wq) ----
__global__ __launch_bounds__(256)
void transpose_kernel(const float* __restrict__ Wv, const float* __restrict__ Wq,
                      bf16_t* __restrict__ WT) {
    __shared__ float Tl[64][65];
    const int bid = blockIdx.x;
    const int s  = bid / 144;
    const int t  = bid % 144;
    const int th = t / 12, ta = t % 12;
    const float* src = (s < S_) ? (Wv + (size_t)s * H_ * A_) : Wq;
    const int tid = threadIdx.x;

    const int r = tid >> 4, c = (tid & 15) * 4;
    #pragma unroll
    for (int i = 0; i < 4; ++i) {
        const int row = i * 16 + r;
        float4 v = *reinterpret_cast<const float4*>(src + (size_t)(th*64 + row) * A_ + ta*64 + c);
        Tl[row][c+0] = v.x; Tl[row][c+1] = v.y; Tl[row][c+2] = v.z; Tl[row][c+3] = v.w;
    }
    __syncthreads();
    bf16_t* dstbase = WT + (size_t)s * A_ * H_ + (size_t)th * 64;
    #pragma unroll
    for (int i = 0; i < 2; ++i) {
        const int ch = tid + i * 256;
        const int a = ch >> 3, hc = ch & 7;
        bf16x8 o;
        #pragma unroll
        for (int j = 0; j < 8; ++j) o[j] = (bf16_t)Tl[hc*8 + j][a];
        *reinterpret_cast<bf16x8*>(dstbase + (size_t)(ta*64 + a) * H_ + hc*8) = o;
    }
}

// ---- main GEMM: 128x128 tile, BK=64, double-buffered reg-staged pipeline.
//      Loads for tile t+1 fly across a RAW s_barrier (no vmcnt drain) and
//      complete under tile t's MFMA. One barrier per iter. ----
__global__ __launch_bounds__(256)
void gemm_kernel(const float* __restrict__ topic,
                 const float* __restrict__ image,
                 const float* __restrict__ text,
                 const bf16_t* __restrict__ WT,
                 const float* __restrict__ bq,
                 const float* __restrict__ bv,
                 bf16_t* __restrict__ Vws, float* __restrict__ Qws)
{
    __shared__ bf16_t Al[2][128 * 64];   // 16 KB per buffer
    __shared__ bf16_t Bl[2][128 * 64];   // total 64 KB

    // XCD-chunked bijective remap for grid 1158 (q=144, r=6) [T1/m204]
    const int b0 = blockIdx.x;
    const int xcd = b0 & 7, ii = b0 >> 3;
    const int bid = (xcd < 6) ? (xcd * 145 + ii) : (870 + (xcd - 6) * 144 + ii);

    const int tid = threadIdx.x;
    const bool isQ = (bid >= S_ * 18);
    int s, tm, tn;
    if (isQ) { s = S_; tm = 0; tn = bid - S_ * 18; }
    else     { s = bid / 18; const int t = bid % 18; tm = t / 6; tn = t % 6; }

    // ---- staging geometry: row r = tid>>1 (shared by A and B), half h = tid&1 ----
    const int r  = tid >> 1;
    const int h  = tid & 1;
    const float* Ap;                      // f32, 32 floats (8 float4) per iter
    if (isQ || tm == 0) Ap = topic + (size_t)r * H_ + h * 32;
    else if (tm == 1)   Ap = image + ((size_t)s * B_ + r) * H_ + h * 32;
    else                Ap = text  + ((size_t)s * B_ + r) * H_ + h * 32;
    const bf16_t* Bp = WT + (size_t)s * A_ * H_ + (size_t)(tn * 128 + r) * H_ + h * 32;
    const int rk = r & 7;                 // swizzle key

    const int wv = tid >> 6, lane = tid & 63;
    const int wr = wv >> 1, wc = wv & 1;
    const int fr = lane & 15, fg = lane >> 4;
    const int fx = fr & 7;

    f32x4 acc[4][4];
    #pragma unroll
    for (int i = 0; i < 4; ++i)
        #pragma unroll
        for (int j = 0; j < 4; ++j)
            acc[i][j] = (f32x4){0.f, 0.f, 0.f, 0.f};

    // ---- prologue: load + stage tile 0 into buffer 0 ----
    float4 fa[8], fb[4];
    {
        const float4* ap = reinterpret_cast<const float4*>(Ap);
        const float4* bp = reinterpret_cast<const float4*>(Bp);
        #pragma unroll
        for (int i = 0; i < 8; ++i) fa[i] = ap[i];
        #pragma unroll
        for (int i = 0; i < 4; ++i) fb[i] = bp[i];
        #pragma unroll
        for (int j = 0; j < 4; ++j) {
            const int cs = ((h * 4 + j) ^ rk) * 8;
            *reinterpret_cast<bf16x8*>(&Al[0][r * 64 + cs]) = pack8(fa[2*j], fa[2*j+1]);
            *reinterpret_cast<bf16x8*>(&Bl[0][r * 64 + cs]) = *reinterpret_cast<const bf16x8*>(&fb[j]);
        }
    }

    for (int t = 0; t < NT; ++t) {
        const int cur = t & 1, nxt = cur ^ 1;
        // issue next tile's global loads (complete under this tile's compute)
        float4 na[8], nb[4];
        if (t < NT - 1) {
            const float4* ap = reinterpret_cast<const float4*>(Ap + (t + 1) * 64);
            const float4* bp = reinterpret_cast<const float4*>(Bp + (t + 1) * 64);
            #pragma unroll
            for (int i = 0; i < 8; ++i) na[i] = ap[i];
            #pragma unroll
            for (int i = 0; i < 4; ++i) nb[i] = bp[i];
        }

        barrier_keep_loads();   // tile t's LDS writes visible; prefetch stays in flight

        bf16x8 af[2][4], bfv[2][4];
        #pragma unroll
        for (int kk = 0; kk < 2; ++kk) {
            #pragma unroll
            for (int mi = 0; mi < 4; ++mi)
                af[kk][mi] = *reinterpret_cast<const bf16x8*>(
                    &Al[cur][(wr*64 + mi*16 + fr) * 64 + ((((kk<<2)|fg)) ^ fx) * 8]);
            #pragma unroll
            for (int ni = 0; ni < 4; ++ni)
                bfv[kk][ni] = *reinterpret_cast<const bf16x8*>(
                    &Bl[cur][(wc*64 + ni*16 + fr) * 64 + ((((kk<<2)|fg)) ^ fx) * 8]);
        }
        #pragma unroll
        for (int kk = 0; kk < 2; ++kk)
            #pragma unroll
            for (int mi = 0; mi < 4; ++mi)
                #pragma unroll
                for (int ni = 0; ni < 4; ++ni)
                    acc[mi][ni] = __builtin_amdgcn_mfma_f32_16x16x32_bf16(
                        af[kk][mi], bfv[kk][ni], acc[mi][ni], 0, 0, 0);

        // stage tile t+1 into the other buffer (its readers all passed the
        // barrier above; compiler's vmcnt deps gate on na/nb arrival)
        if (t < NT - 1) {
            #pragma unroll
            for (int j = 0; j < 4; ++j) {
                const int cs = ((h * 4 + j) ^ rk) * 8;
                *reinterpret_cast<bf16x8*>(&Al[nxt][r * 64 + cs]) = pack8(na[2*j], na[2*j+1]);
                *reinterpret_cast<bf16x8*>(&Bl[nxt][r * 64 + cs]) = *reinterpret_cast<const bf16x8*>(&nb[j]);
            }
        }
    }

    // ---- epilogue: C/D map col = lane&15, row = (lane>>4)*4 + j ----
    if (isQ) {
        #pragma unroll
        for (int ni = 0; ni < 4; ++ni) {
            const int n = tn*128 + wc*64 + ni*16 + fr;
            const float bias = bq[n];
            #pragma unroll
            for (int mi = 0; mi < 4; ++mi)
                #pragma unroll
                for (int j = 0; j < 4; ++j) {
                    const int m = wr*64 + mi*16 + fg*4 + j;
                    Qws[(size_t)m * A_ + n] = acc[mi][ni][j] + bias;
                }
        }
    } else {
        const float* bvrow = bv + (size_t)s * A_;
        #pragma unroll
        for (int ni = 0; ni < 4; ++ni) {
            const int n = tn*128 + wc*64 + ni*16 + fr;
            const float bias = bvrow[n];
            #pragma unroll
            for (int mi = 0; mi < 4; ++mi)
                #pragma unroll
                for (int j = 0; j < 4; ++j) {
                    const int b = wr*64 + mi*16 + fg*4 + j;
                    Vws[(((size_t)s * B_ + b) * 3 + tm) * A_ + n] = (bf16_t)(acc[mi][ni][j] + bias);
                }
        }
    }
}

// ---- attention combine: one wave per (s,b) ----
__global__ __launch_bounds__(256)
void mm_attn_kernel(const bf16_t* __restrict__ Vws,
                    const float* __restrict__ Qws,
                    float* __restrict__ out)
{
    const int wave = threadIdx.x >> 6;
    const int lane = threadIdx.x & 63;
    const int p = blockIdx.x * 4 + wave;
    const int s = p >> 7;
    const int b = p & 127;
    const float*  qrow  = Qws + (size_t)b * A_;
    const bf16_t* vbase = Vws + ((size_t)s * B_ + b) * 3 * A_;

    float4 qv[3];
    bf16x4 vv[3][3];
    float p0 = 0.f, p1 = 0.f, p2 = 0.f;
    #pragma unroll
    for (int j = 0; j < 3; ++j) {
        const int a = lane * 4 + j * 256;
        qv[j]    = *reinterpret_cast<const float4*>(qrow + a);
        vv[0][j] = *reinterpret_cast<const bf16x4*>(vbase + 0*A_ + a);
        vv[1][j] = *reinterpret_cast<const bf16x4*>(vbase + 1*A_ + a);
        vv[2][j] = *reinterpret_cast<const bf16x4*>(vbase + 2*A_ + a);
        p0 += qv[j].x*(float)vv[0][j][0] + qv[j].y*(float)vv[0][j][1]
            + qv[j].z*(float)vv[0][j][2] + qv[j].w*(float)vv[0][j][3];
        p1 += qv[j].x*(float)vv[1][j][0] + qv[j].y*(float)vv[1][j][1]
            + qv[j].z*(float)vv[1][j][2] + qv[j].w*(float)vv[1][j][3];
        p2 += qv[j].x*(float)vv[2][j][0] + qv[j].y*(float)vv[2][j][1]
            + qv[j].z*(float)vv[2][j][2] + qv[j].w*(float)vv[2][j][3];
    }
    #pragma unroll
    for (int d = 1; d < 64; d <<= 1) {
        p0 += __shfl_xor(p0, d);
        p1 += __shfl_xor(p1, d);
        p2 += __shfl_xor(p2, d);
    }
    const float norm = 0.03608439182435161f;   // 1/sqrt(768)
    const float s0 = p0 * norm, s1 = p1 * norm, s2 = p2 * norm;
    const float mx = fmaxf(s0, fmaxf(s1, s2));
    const float e0 = expf(s0 - mx), e1 = expf(s1 - mx), e2 = expf(s2 - mx);
    const float inv = 1.f / (e0 + e1 + e2);
    const float a0 = e0 * inv, a1 = e1 * inv, a2 = e2 * inv;

    float* orow = out + ((size_t)s * B_ + b) * A_;
    #pragma unroll
    for (int j = 0; j < 3; ++j) {
        const int a = lane * 4 + j * 256;
        float4 o;
        o.x = a0*(float)vv[0][j][0] + a1*(float)vv[1][j][0] + a2*(float)vv[2][j][0];
        o.y = a0*(float)vv[0][j][1] + a1*(float)vv[1][j][1] + a2*(float)vv[2][j][1];
        o.z = a0*(float)vv[0][j][2] + a1*(float)vv[1][j][2] + a2*(float)vv[2][j][2];
        o.w = a0*(float)vv[0][j][3] + a1*(float)vv[1][j][3] + a2*(float)vv[2][j][3];
        *reinterpret_cast<float4*>(orow + a) = o;
    }
}

// ============================================================================
// FALLBACK PATH (round-1 GEMM, used only if ws_size is too small)
// ============================================================================
#define LDSPAD 40
__global__ __launch_bounds__(256, 2)
void mm_gemm_kernel(const float* __restrict__ topic,
                    const float* __restrict__ image,
                    const float* __restrict__ text,
                    const float* __restrict__ Wq,
                    const float* __restrict__ bq,
                    const float* __restrict__ Wv,
                    const float* __restrict__ bv,
                    bf16_t* __restrict__ Vws,
                    float*  __restrict__ Qws)
{
    __shared__ bf16_t Alds[128][LDSPAD];
    __shared__ bf16_t Blds[128][LDSPAD];

    const int bid = blockIdx.x;
    const int tid = threadIdx.x;
    const bool isQ = (bid >= S_ * 18);
    int s, tm, tn;
    if (isQ) { s = 0; tm = 0; tn = bid - S_ * 18; }
    else     { s = bid / 18; const int t = bid % 18; tm = t / 6; tn = t % 6; }

    const int ar  = tid >> 1;
    const int aks = (tid & 1) * 16;
    const float* arow;
    if (isQ) {
        arow = topic + (size_t)ar * H_;
    } else {
        const int am  = tm * 128 + ar;
        const int sel = am >> 7;
        const int b   = am & 127;
        if (sel == 0)      arow = topic + (size_t)b * H_;
        else if (sel == 1) arow = image + ((size_t)s * B_ + b) * H_;
        else               arow = text  + ((size_t)s * B_ + b) * H_;
    }
    const int arot = (ar >> 3) & 3;

    const int bn  = tid & 127;
    const int bks = (tid >> 7) * 16;
    const float* wbase = isQ ? Wq : (Wv + (size_t)s * H_ * A_);
    const float* bcolp = wbase + (size_t)(tn * 128 + bn);
    const int brot = (bn >> 3) & 3;

    const int wave = tid >> 6;
    const int lane = tid & 63;
    const int wr = wave >> 1;
    const int wc = wave & 1;
    const int fr = lane & 15;
    const int fg = lane >> 4;

    f32x4 acc[4][4];
    #pragma unroll
    for (int i = 0; i < 4; ++i)
        #pragma unroll
        for (int j = 0; j < 4; ++j)
            acc[i][j] = (f32x4){0.f, 0.f, 0.f, 0.f};

    for (int k0 = 0; k0 < H_; k0 += 32) {
        float4 av[4];
        const float4* ap = reinterpret_cast<const float4*>(arow + k0 + aks);
        #pragma unroll
        for (int i = 0; i < 4; ++i) av[i] = ap[i];
        float bvr[16];
        #pragma unroll
        for (int j = 0; j < 16; ++j) bvr[j] = bcolp[(size_t)(k0 + bks + j) * A_];

        __syncthreads();

        #pragma unroll
        for (int i = 0; i < 4; ++i) {
            const int j = (i + arot) & 3;
            bf16x4 c;
            c[0] = (bf16_t)av[j].x; c[1] = (bf16_t)av[j].y;
            c[2] = (bf16_t)av[j].z; c[3] = (bf16_t)av[j].w;
            *reinterpret_cast<bf16x4*>(&Alds[ar][aks + 4*j]) = c;
        }
        #pragma unroll
        for (int i = 0; i < 4; ++i) {
            const int j = (i + brot) & 3;
            bf16x4 c;
            c[0] = (bf16_t)bvr[4*j+0]; c[1] = (bf16_t)bvr[4*j+1];
            c[2] = (bf16_t)bvr[4*j+2]; c[3] = (bf16_t)bvr[4*j+3];
            *reinterpret_cast<bf16x4*>(&Blds[bn][bks + 4*j]) = c;
        }
        __syncthreads();

        bf16x8 afrag[4], bfrag[4];
        #pragma unroll
        for (int mi = 0; mi < 4; ++mi)
            afrag[mi] = *reinterpret_cast<const bf16x8*>(&Alds[wr*64 + mi*16 + fr][fg*8]);
        #pragma unroll
        for (int ni = 0; ni < 4; ++ni)
            bfrag[ni] = *reinterpret_cast<const bf16x8*>(&Blds[wc*64 + ni*16 + fr][fg*8]);
        #pragma unroll
        for (int mi = 0; mi < 4; ++mi)
            #pragma unroll
            for (int ni = 0; ni < 4; ++ni)
                acc[mi][ni] = __builtin_amdgcn_mfma_f32_16x16x32_bf16(
                    afrag[mi], bfrag[ni], acc[mi][ni], 0, 0, 0);
    }

    if (isQ) {
        #pragma unroll
        for (int ni = 0; ni < 4; ++ni) {
            const int n = tn*128 + wc*64 + ni*16 + fr;
            const float bias = bq[n];
            #pragma unroll
            for (int mi = 0; mi < 4; ++mi)
                #pragma unroll
                for (int j = 0; j < 4; ++j) {
                    const int m = wr*64 + mi*16 + fg*4 + j;
                    Qws[(size_t)m * A_ + n] = acc[mi][ni][j] + bias;
                }
        }
    } else {
        const float* bvrow = bv + (size_t)s * A_;
        #pragma unroll
        for (int ni = 0; ni < 4; ++ni) {
            const int n = tn*128 + wc*64 + ni*16 + fr;
            const float bias = bvrow[n];
            #pragma unroll
            for (int mi = 0; mi < 4; ++mi)
                #pragma unroll
                for (int j = 0; j < 4; ++j) {
                    const int b = wr*64 + mi*16 + fg*4 + j;
                    Vws[(((size_t)s * B_ + b) * 3 + tm) * A_ + n] = (bf16_t)(acc[mi][ni][j] + bias);
                }
        }
    }
}

// ============================================================================
extern "C" void kernel_launch(void* const* d_in, const int* in_sizes, int n_in,
                              void* d_out, int out_size, void* d_ws, size_t ws_size,
                              hipStream_t stream)
{
    const float* topic = (const float*)d_in[0];
    const float* image = (const float*)d_in[1];
    const float* text  = (const float*)d_in[2];
    const float* Wq    = (const float*)d_in[3];
    const float* bq    = (const float*)d_in[4];
    const float* Wv    = (const float*)d_in[5];
    const float* bv    = (const float*)d_in[6];
    float* out = (float*)d_out;

    const size_t szWT = (size_t)(S_ + 1) * A_ * H_ * sizeof(bf16_t);   // 76,677,120
    const size_t szV  = (size_t)S_ * B_ * 3 * A_ * sizeof(bf16_t);     // 37,748,736
    const size_t szQ  = (size_t)B_ * A_ * sizeof(float);               //    393,216
    const size_t need = szWT + szV + szQ;                              // ~115 MB

    if (ws_size >= need) {
        char* w = (char*)d_ws;
        bf16_t* WT  = (bf16_t*)w;  w += szWT;
        bf16_t* Vws = (bf16_t*)w;  w += szV;
        float*  Qws = (float*) w;

        transpose_kernel<<<(S_+1)*144, 256, 0, stream>>>(Wv, Wq, WT);
        gemm_kernel<<<S_*18 + 6, 256, 0, stream>>>(topic, image, text, WT, bq, bv, Vws, Qws);
        mm_attn_kernel<<<S_*B_/4, 256, 0, stream>>>(Vws, Qws, out);
    } else {
        bf16_t* Vws = (bf16_t*)d_ws;
        float*  Qws = (float*)((char*)d_ws + szV);
        mm_gemm_kernel<<<S_*18 + 6, 256, 0, stream>>>(topic, image, text, Wq, bq, Wv, bv, Vws, Qws);
        mm_attn_kernel<<<S_*B_/4, 256, 0, stream>>>(Vws, Qws, out);
    }
}

// Round 5
// 135.801 us; speedup vs baseline: 1.0520x; 1.0520x over previous
//
#include <hip/hip_runtime.h>
#include <hip/hip_bf16.h>
#include <math.h>

#define S_ 64
#define B_ 128
#define H_ 768
#define A_ 768
#define NT 12            // K-steps: 768 / 64
#define BK 64

typedef __bf16 bf16_t;
typedef __attribute__((ext_vector_type(8))) __bf16 bf16x8;
typedef __attribute__((ext_vector_type(4))) __bf16 bf16x4;
typedef __attribute__((ext_vector_type(4))) float f32x4;

#define TOPIC_N   98304      // 128*768
#define IMG_N   6291456      // 64*128*768

__device__ __forceinline__ bf16x8 pack8(float4 a, float4 b) {
    bf16x8 o;
    o[0]=(bf16_t)a.x; o[1]=(bf16_t)a.y; o[2]=(bf16_t)a.z; o[3]=(bf16_t)a.w;
    o[4]=(bf16_t)b.x; o[5]=(bf16_t)b.y; o[6]=(bf16_t)b.z; o[7]=(bf16_t)b.w;
    return o;
}

// lgkm-only barrier: LDS writes visible, outstanding global/glds stay in flight
__device__ __forceinline__ void barrier_keep_loads() {
    asm volatile("s_waitcnt lgkmcnt(0)" ::: "memory");
    __builtin_amdgcn_sched_barrier(0);
    __builtin_amdgcn_s_barrier();
    __builtin_amdgcn_sched_barrier(0);
}

__device__ __forceinline__ void glds16f(const float* g, float* l) {
    __builtin_amdgcn_global_load_lds(
        (const __attribute__((address_space(1))) uint32_t*)g,
        (__attribute__((address_space(3))) uint32_t*)l, 16, 0, 0);
}
__device__ __forceinline__ void glds16b(const bf16_t* g, bf16_t* l) {
    __builtin_amdgcn_global_load_lds(
        (const __attribute__((address_space(1))) uint32_t*)g,
        (__attribute__((address_space(3))) uint32_t*)l, 16, 0, 0);
}

// ============================================================================
// FAST PATH
// ============================================================================

// ---- prep: [topic; image; text] f32 -> bf16, one linear pass ----
__global__ __launch_bounds__(256)
void convert_kernel(const float* __restrict__ topic, const float* __restrict__ image,
                    const float* __restrict__ text, bf16_t* __restrict__ out) {
    const int i = blockIdx.x * 256 + threadIdx.x;      // 8 elems each
    const int T8 = TOPIC_N / 8, I8 = IMG_N / 8;
    const size_t e = (size_t)i * 8;
    const float* src; size_t off;
    if (i < T8)           { src = topic; off = e; }
    else if (i < T8 + I8) { src = image; off = e - TOPIC_N; }
    else                  { src = text;  off = e - TOPIC_N - IMG_N; }
    const float4* p = reinterpret_cast<const float4*>(src + off);
    float4 a = p[0], b = p[1];
    *reinterpret_cast<bf16x8*>(out + e) = pack8(a, b);
}

// ---- fused GEMM: 128x128 tile, BK=64, 512 thr (8 waves 2Mx4N).
//      W f32 glds'd [k][n] into LDS dbuf (no registers -> compiler can't sink
//      the prefetch); transposed+cvt LDS->LDS to bf16 B-tile per iter.
//      A bf16 glds'd with pre-swizzled source. Prefetch t+1 issued mid-iter,
//      drained at end-of-iter __syncthreads; mid-iter barrier is lgkm-only. ----
__global__ __launch_bounds__(512)
void gemm_fused(const float* __restrict__ Wv, const float* __restrict__ Wq,
                const bf16_t* __restrict__ actB,
                const float* __restrict__ bq, const float* __restrict__ bv,
                bf16_t* __restrict__ Vws, float* __restrict__ Qws)
{
    __shared__ float  W1[2][BK * 128];    // W staging [k][n] f32, 2x32 KB
    __shared__ bf16_t Al[2][128 * BK];    // A [m][k] bf16 XOR-swizzled, 2x16 KB
    __shared__ bf16_t Bl[128 * BK];       // B [n][k] bf16 swizzled, 16 KB

    // XCD-chunked bijective remap for grid 1158 (q=144, r=6) [T1/m204]
    const int b0 = blockIdx.x;
    const int xcd = b0 & 7, ii = b0 >> 3;
    const int bid = (xcd < 6) ? (xcd * 145 + ii) : (870 + (xcd - 6) * 144 + ii);

    const int tid = threadIdx.x;
    const bool isQ = (bid >= S_ * 18);
    int s, tm, tn;
    if (isQ) { s = S_; tm = 0; tn = bid - S_ * 18; }
    else     { s = bid / 18; const int t = bid % 18; tm = t / 6; tn = t % 6; }

    const float* Wsl = isQ ? Wq : (Wv + (size_t)s * H_ * A_);
    const bf16_t* Apanel;
    if (isQ || tm == 0) Apanel = actB;
    else if (tm == 1)   Apanel = actB + TOPIC_N + (size_t)s * B_ * H_;
    else                Apanel = actB + TOPIC_N + IMG_N + (size_t)s * B_ * H_;

    const int wv = tid >> 6, lane = tid & 63;
    const int wr = wv >> 2, wc = wv & 3;          // 2M x 4N waves: 64x32 each
    const int fr = lane & 15, fg = lane >> 4;

    // transpose-phase assignment: n fast with lane (2-way bank alias = free)
    const int xn  = tid & 127;                     // B row (n)
    const int xc0 = tid >> 7;                      // chunk 0..3 (and +4)
    const int xpk = xn & 7, xrot = (xn >> 3) & 7;

    f32x4 acc[4][2];
    #pragma unroll
    for (int i = 0; i < 4; ++i)
        #pragma unroll
        for (int j = 0; j < 2; ++j)
            acc[i][j] = (f32x4){0.f, 0.f, 0.f, 0.f};

    // ---- staging issue macros (no register consumers!) ----
    auto stageW = [&](int k0, int buf) {
        #pragma unroll
        for (int q = 0; q < 4; ++q) {
            const int p = (wv * 4 + q) * 64 + lane;       // 16B chunk id
            const int k = p >> 5, c = p & 31;
            glds16f(Wsl + (size_t)(k0 + k) * A_ + tn * 128 + c * 4,
                    &W1[buf][(wv * 4 + q) * 256]);
        }
    };
    auto stageA = [&](int k0, int buf) {
        #pragma unroll
        for (int q = 0; q < 2; ++q) {
            const int p = (wv * 2 + q) * 64 + lane;
            const int r = p >> 3, c = p & 7;
            glds16b(Apanel + (size_t)r * H_ + k0 + ((c ^ (r & 7)) * 8),
                    &Al[buf][(wv * 2 + q) * 512]);
        }
    };

    // ---- prologue: stage tile 0 ----
    stageW(0, 0);
    stageA(0, 0);
    __syncthreads();

    int cur = 0;
    for (int t = 0; t < NT; ++t) {
        const int nxt = cur ^ 1;
        if (t < NT - 1) {                    // prefetch t+1 (flies under everything)
            stageW((t + 1) * BK, nxt);
            stageA((t + 1) * BK, nxt);
        }
        // transpose W1[cur] [k][n] f32 -> Bl [n][k] bf16 (swizzled)
        {
            float v[16];
            #pragma unroll
            for (int j = 0; j < 8; ++j) v[j]     = W1[cur][(xc0 * 8 + j) * 128 + xn];
            #pragma unroll
            for (int j = 0; j < 8; ++j) v[8 + j] = W1[cur][((xc0 + 4) * 8 + j) * 128 + xn];
            bf16x8 o0, o1;
            #pragma unroll
            for (int j = 0; j < 8; ++j) { o0[j] = (bf16_t)v[j]; o1[j] = (bf16_t)v[8 + j]; }
            *reinterpret_cast<bf16x8*>(&Bl[xn * 64 + ((((xc0    ) ^ xpk) + xrot) & 7) * 8]) = o0;
            *reinterpret_cast<bf16x8*>(&Bl[xn * 64 + ((((xc0 + 4) ^ xpk) + xrot) & 7) * 8]) = o1;
        }
        barrier_keep_loads();                // Bl visible; prefetch still in flight

        bf16x8 af[2][4], bfv[2][2];
        #pragma unroll
        for (int kk = 0; kk < 2; ++kk) {
            const int lc = (kk << 2) | fg;
            #pragma unroll
            for (int mi = 0; mi < 4; ++mi) {
                const int m = wr * 64 + mi * 16 + fr;
                af[kk][mi] = *reinterpret_cast<const bf16x8*>(
                    &Al[cur][m * 64 + (lc ^ (m & 7)) * 8]);
            }
            #pragma unroll
            for (int ni = 0; ni < 2; ++ni) {
                const int n = wc * 32 + ni * 16 + fr;
                bfv[kk][ni] = *reinterpret_cast<const bf16x8*>(
                    &Bl[n * 64 + (((lc ^ (n & 7)) + ((n >> 3) & 7)) & 7) * 8]);
            }
        }
        #pragma unroll
        for (int kk = 0; kk < 2; ++kk)
            #pragma unroll
            for (int mi = 0; mi < 4; ++mi)
                #pragma unroll
                for (int ni = 0; ni < 2; ++ni)
                    acc[mi][ni] = __builtin_amdgcn_mfma_f32_16x16x32_bf16(
                        af[kk][mi], bfv[kk][ni], acc[mi][ni], 0, 0, 0);

        __syncthreads();                     // drains prefetch (mostly landed) + LDS
        cur = nxt;
    }

    // ---- epilogue: C/D map col = lane&15, row = (lane>>4)*4 + j ----
    if (isQ) {
        #pragma unroll
        for (int ni = 0; ni < 2; ++ni) {
            const int n = tn * 128 + wc * 32 + ni * 16 + fr;
            const float bias = bq[n];
            #pragma unroll
            for (int mi = 0; mi < 4; ++mi)
                #pragma unroll
                for (int j = 0; j < 4; ++j) {
                    const int m = wr * 64 + mi * 16 + fg * 4 + j;
                    Qws[(size_t)m * A_ + n] = acc[mi][ni][j] + bias;
                }
        }
    } else {
        const float* bvrow = bv + (size_t)s * A_;
        #pragma unroll
        for (int ni = 0; ni < 2; ++ni) {
            const int n = tn * 128 + wc * 32 + ni * 16 + fr;
            const float bias = bvrow[n];
            #pragma unroll
            for (int mi = 0; mi < 4; ++mi)
                #pragma unroll
                for (int j = 0; j < 4; ++j) {
                    const int b = wr * 64 + mi * 16 + fg * 4 + j;
                    Vws[(((size_t)s * B_ + b) * 3 + tm) * A_ + n] = (bf16_t)(acc[mi][ni][j] + bias);
                }
        }
    }
}

// ---- attention combine: one wave per (s,b) ----
__global__ __launch_bounds__(256)
void mm_attn_kernel(const bf16_t* __restrict__ Vws,
                    const float* __restrict__ Qws,
                    float* __restrict__ out)
{
    const int wave = threadIdx.x >> 6;
    const int lane = threadIdx.x & 63;
    const int p = blockIdx.x * 4 + wave;
    const int s = p >> 7;
    const int b = p & 127;
    const float*  qrow  = Qws + (size_t)b * A_;
    const bf16_t* vbase = Vws + ((size_t)s * B_ + b) * 3 * A_;

    float4 qv[3];
    bf16x4 vv[3][3];
    float p0 = 0.f, p1 = 0.f, p2 = 0.f;
    #pragma unroll
    for (int j = 0; j < 3; ++j) {
        const int a = lane * 4 + j * 256;
        qv[j]    = *reinterpret_cast<const float4*>(qrow + a);
        vv[0][j] = *reinterpret_cast<const bf16x4*>(vbase + 0*A_ + a);
        vv[1][j] = *reinterpret_cast<const bf16x4*>(vbase + 1*A_ + a);
        vv[2][j] = *reinterpret_cast<const bf16x4*>(vbase + 2*A_ + a);
        p0 += qv[j].x*(float)vv[0][j][0] + qv[j].y*(float)vv[0][j][1]
            + qv[j].z*(float)vv[0][j][2] + qv[j].w*(float)vv[0][j][3];
        p1 += qv[j].x*(float)vv[1][j][0] + qv[j].y*(float)vv[1][j][1]
            + qv[j].z*(float)vv[1][j][2] + qv[j].w*(float)vv[1][j][3];
        p2 += qv[j].x*(float)vv[2][j][0] + qv[j].y*(float)vv[2][j][1]
            + qv[j].z*(float)vv[2][j][2] + qv[j].w*(float)vv[2][j][3];
    }
    #pragma unroll
    for (int d = 1; d < 64; d <<= 1) {
        p0 += __shfl_xor(p0, d);
        p1 += __shfl_xor(p1, d);
        p2 += __shfl_xor(p2, d);
    }
    const float norm = 0.03608439182435161f;   // 1/sqrt(768)
    const float s0 = p0 * norm, s1 = p1 * norm, s2 = p2 * norm;
    const float mx = fmaxf(s0, fmaxf(s1, s2));
    const float e0 = expf(s0 - mx), e1 = expf(s1 - mx), e2 = expf(s2 - mx);
    const float inv = 1.f / (e0 + e1 + e2);
    const float a0 = e0 * inv, a1 = e1 * inv, a2 = e2 * inv;

    float* orow = out + ((size_t)s * B_ + b) * A_;
    #pragma unroll
    for (int j = 0; j < 3; ++j) {
        const int a = lane * 4 + j * 256;
        float4 o;
        o.x = a0*(float)vv[0][j][0] + a1*(float)vv[1][j][0] + a2*(float)vv[2][j][0];
        o.y = a0*(float)vv[0][j][1] + a1*(float)vv[1][j][1] + a2*(float)vv[2][j][1];
        o.z = a0*(float)vv[0][j][2] + a1*(float)vv[1][j][2] + a2*(float)vv[2][j][2];
        o.w = a0*(float)vv[0][j][3] + a1*(float)vv[1][j][3] + a2*(float)vv[2][j][3];
        *reinterpret_cast<float4*>(orow + a) = o;
    }
}

// ============================================================================
// FALLBACK PATH (round-1 GEMM, used only if ws_size is too small)
// ============================================================================
#define LDSPAD 40
__global__ __launch_bounds__(256, 2)
void mm_gemm_kernel(const float* __restrict__ topic,
                    const float* __restrict__ image,
                    const float* __restrict__ text,
                    const float* __restrict__ Wq,
                    const float* __restrict__ bq,
                    const float* __restrict__ Wv,
                    const float* __restrict__ bv,
                    bf16_t* __restrict__ Vws,
                    float*  __restrict__ Qws)
{
    __shared__ bf16_t Alds[128][LDSPAD];
    __shared__ bf16_t Blds[128][LDSPAD];

    const int bid = blockIdx.x;
    const int tid = threadIdx.x;
    const bool isQ = (bid >= S_ * 18);
    int s, tm, tn;
    if (isQ) { s = 0; tm = 0; tn = bid - S_ * 18; }
    else     { s = bid / 18; const int t = bid % 18; tm = t / 6; tn = t % 6; }

    const int ar  = tid >> 1;
    const int aks = (tid & 1) * 16;
    const float* arow;
    if (isQ) {
        arow = topic + (size_t)ar * H_;
    } else {
        const int am  = tm * 128 + ar;
        const int sel = am >> 7;
        const int b   = am & 127;
        if (sel == 0)      arow = topic + (size_t)b * H_;
        else if (sel == 1) arow = image + ((size_t)s * B_ + b) * H_;
        else               arow = text  + ((size_t)s * B_ + b) * H_;
    }
    const int arot = (ar >> 3) & 3;

    const int bn  = tid & 127;
    const int bks = (tid >> 7) * 16;
    const float* wbase = isQ ? Wq : (Wv + (size_t)s * H_ * A_);
    const float* bcolp = wbase + (size_t)(tn * 128 + bn);
    const int brot = (bn >> 3) & 3;

    const int wave = tid >> 6;
    const int lane = tid & 63;
    const int wr = wave >> 1;
    const int wc = wave & 1;
    const int fr = lane & 15;
    const int fg = lane >> 4;

    f32x4 acc[4][4];
    #pragma unroll
    for (int i = 0; i < 4; ++i)
        #pragma unroll
        for (int j = 0; j < 4; ++j)
            acc[i][j] = (f32x4){0.f, 0.f, 0.f, 0.f};

    for (int k0 = 0; k0 < H_; k0 += 32) {
        float4 av[4];
        const float4* ap = reinterpret_cast<const float4*>(arow + k0 + aks);
        #pragma unroll
        for (int i = 0; i < 4; ++i) av[i] = ap[i];
        float bvr[16];
        #pragma unroll
        for (int j = 0; j < 16; ++j) bvr[j] = bcolp[(size_t)(k0 + bks + j) * A_];

        __syncthreads();

        #pragma unroll
        for (int i = 0; i < 4; ++i) {
            const int j = (i + arot) & 3;
            bf16x4 c;
            c[0] = (bf16_t)av[j].x; c[1] = (bf16_t)av[j].y;
            c[2] = (bf16_t)av[j].z; c[3] = (bf16_t)av[j].w;
            *reinterpret_cast<bf16x4*>(&Alds[ar][aks + 4*j]) = c;
        }
        #pragma unroll
        for (int i = 0; i < 4; ++i) {
            const int j = (i + brot) & 3;
            bf16x4 c;
            c[0] = (bf16_t)bvr[4*j+0]; c[1] = (bf16_t)bvr[4*j+1];
            c[2] = (bf16_t)bvr[4*j+2]; c[3] = (bf16_t)bvr[4*j+3];
            *reinterpret_cast<bf16x4*>(&Blds[bn][bks + 4*j]) = c;
        }
        __syncthreads();

        bf16x8 afrag[4], bfrag[4];
        #pragma unroll
        for (int mi = 0; mi < 4; ++mi)
            afrag[mi] = *reinterpret_cast<const bf16x8*>(&Alds[wr*64 + mi*16 + fr][fg*8]);
        #pragma unroll
        for (int ni = 0; ni < 4; ++ni)
            bfrag[ni] = *reinterpret_cast<const bf16x8*>(&Blds[wc*64 + ni*16 + fr][fg*8]);
        #pragma unroll
        for (int mi = 0; mi < 4; ++mi)
            #pragma unroll
            for (int ni = 0; ni < 4; ++ni)
                acc[mi][ni] = __builtin_amdgcn_mfma_f32_16x16x32_bf16(
                    afrag[mi], bfrag[ni], acc[mi][ni], 0, 0, 0);
    }

    if (isQ) {
        #pragma unroll
        for (int ni = 0; ni < 4; ++ni) {
            const int n = tn*128 + wc*64 + ni*16 + fr;
            const float bias = bq[n];
            #pragma unroll
            for (int mi = 0; mi < 4; ++mi)
                #pragma unroll
                for (int j = 0; j < 4; ++j) {
                    const int m = wr*64 + mi*16 + fg*4 + j;
                    Qws[(size_t)m * A_ + n] = acc[mi][ni][j] + bias;
                }
        }
    } else {
        const float* bvrow = bv + (size_t)s * A_;
        #pragma unroll
        for (int ni = 0; ni < 4; ++ni) {
            const int n = tn*128 + wc*64 + ni*16 + fr;
            const float bias = bvrow[n];
            #pragma unroll
            for (int mi = 0; mi < 4; ++mi)
                #pragma unroll
                for (int j = 0; j < 4; ++j) {
                    const int b = wr*64 + mi*16 + fg*4 + j;
                    Vws[(((size_t)s * B_ + b) * 3 + tm) * A_ + n] = (bf16_t)(acc[mi][ni][j] + bias);
                }
        }
    }
}

// ============================================================================
extern "C" void kernel_launch(void* const* d_in, const int* in_sizes, int n_in,
                              void* d_out, int out_size, void* d_ws, size_t ws_size,
                              hipStream_t stream)
{
    const float* topic = (const float*)d_in[0];
    const float* image = (const float*)d_in[1];
    const float* text  = (const float*)d_in[2];
    const float* Wq    = (const float*)d_in[3];
    const float* bq    = (const float*)d_in[4];
    const float* Wv    = (const float*)d_in[5];
    const float* bv    = (const float*)d_in[6];
    float* out = (float*)d_out;

    const size_t szAct = (size_t)(TOPIC_N + 2 * IMG_N) * sizeof(bf16_t);  // 25,362,432
    const size_t szV   = (size_t)S_ * B_ * 3 * A_ * sizeof(bf16_t);       // 37,748,736
    const size_t szQ   = (size_t)B_ * A_ * sizeof(float);                 //    393,216
    const size_t need  = szAct + szV + szQ;                               // ~63.5 MB

    if (ws_size >= need) {
        char* w = (char*)d_ws;
        bf16_t* actB = (bf16_t*)w;  w += szAct;
        bf16_t* Vws  = (bf16_t*)w;  w += szV;
        float*  Qws  = (float*) w;

        convert_kernel<<<(TOPIC_N + 2 * IMG_N) / 8 / 256, 256, 0, stream>>>(topic, image, text, actB);
        gemm_fused<<<S_ * 18 + 6, 512, 0, stream>>>(Wv, Wq, actB, bq, bv, Vws, Qws);
        mm_attn_kernel<<<S_ * B_ / 4, 256, 0, stream>>>(Vws, Qws, out);
    } else {
        bf16_t* Vws = (bf16_t*)d_ws;
        float*  Qws = (float*)((char*)d_ws + szV);
        mm_gemm_kernel<<<S_ * 18 + 6, 256, 0, stream>>>(topic, image, text, Wq, bq, Wv, bv, Vws, Qws);
        mm_attn_kernel<<<S_ * B_ / 4, 256, 0, stream>>>(Vws, Qws, out);
    }
}

// Round 6
// 117.883 us; speedup vs baseline: 1.2118x; 1.1520x over previous
//
#include <hip/hip_runtime.h>
#include <hip/hip_bf16.h>
#include <math.h>

#define S_ 64
#define B_ 128
#define H_ 768
#define A_ 768
#define BK 32
#define NT2 24           // K-steps: 768/32

typedef __bf16 bf16_t;
typedef __attribute__((ext_vector_type(8))) __bf16 bf16x8;
typedef __attribute__((ext_vector_type(4))) __bf16 bf16x4;
typedef __attribute__((ext_vector_type(4))) float f32x4;

#define TOPIC_N   98304      // 128*768
#define IMG_N   6291456      // 64*128*768

__device__ __forceinline__ bf16x8 pack8(float4 a, float4 b) {
    bf16x8 o;
    o[0]=(bf16_t)a.x; o[1]=(bf16_t)a.y; o[2]=(bf16_t)a.z; o[3]=(bf16_t)a.w;
    o[4]=(bf16_t)b.x; o[5]=(bf16_t)b.y; o[6]=(bf16_t)b.z; o[7]=(bf16_t)b.w;
    return o;
}

__device__ __forceinline__ void glds16f(const float* g, float* l) {
    __builtin_amdgcn_global_load_lds(
        (const __attribute__((address_space(1))) uint32_t*)g,
        (__attribute__((address_space(3))) uint32_t*)l, 16, 0, 0);
}
__device__ __forceinline__ void glds16b(const bf16_t* g, bf16_t* l) {
    __builtin_amdgcn_global_load_lds(
        (const __attribute__((address_space(1))) uint32_t*)g,
        (__attribute__((address_space(3))) uint32_t*)l, 16, 0, 0);
}

// loop-top sync: wait own glds landed, then join block
__device__ __forceinline__ void vm0_bar() {
    asm volatile("s_waitcnt vmcnt(0)" ::: "memory");
    __builtin_amdgcn_sched_barrier(0);
    __builtin_amdgcn_s_barrier();
    __builtin_amdgcn_sched_barrier(0);
}

// ============================================================================
// FAST PATH
// ============================================================================

// ---- prep: [topic; image; text] f32 -> bf16, one linear pass ----
__global__ __launch_bounds__(256)
void convert_kernel(const float* __restrict__ topic, const float* __restrict__ image,
                    const float* __restrict__ text, bf16_t* __restrict__ out) {
    const int i = blockIdx.x * 256 + threadIdx.x;      // 8 elems each
    const int T8 = TOPIC_N / 8, I8 = IMG_N / 8;
    const size_t e = (size_t)i * 8;
    const float* src; size_t off;
    if (i < T8)           { src = topic; off = e; }
    else if (i < T8 + I8) { src = image; off = e - TOPIC_N; }
    else                  { src = text;  off = e - TOPIC_N - IMG_N; }
    const float4* p = reinterpret_cast<const float4*>(src + off);
    float4 a = p[0], b = p[1];
    *reinterpret_cast<bf16x8*>(out + e) = pack8(a, b);
}

// ---- main GEMM: 128(M)x64(N) tile, BK=32, 256 thr (4 waves, 2Mx2N).
//      W f32 staged [k][n] via glds with rotate-swizzled source (column reads
//      2-way free); B-frags read W1 directly + cvt in reg (no B LDS buffer,
//      no transpose phase). A bf16 via glds, linear. One vmcnt(0)+s_barrier
//      per iter at loop top; 32 KB LDS -> 5 blocks/CU for TLP latency hiding.
__global__ __launch_bounds__(256, 5)
void gemm_direct(const float* __restrict__ Wv, const float* __restrict__ Wq,
                 const bf16_t* __restrict__ actB,
                 const float* __restrict__ bq, const float* __restrict__ bv,
                 bf16_t* __restrict__ Vws, float* __restrict__ Qws)
{
    __shared__ float  W1[2][BK * 64];     // [k][n-chunk swizzled] f32, 8 KB each
    __shared__ bf16_t Al[2][128 * BK];    // [m][k] bf16 linear, 8 KB each

    // XCD-chunked bijective remap, nwg = 2316 (q=289, r=4) [T1/m204]
    const int b0 = blockIdx.x;
    const int xcd = b0 & 7, ii = b0 >> 3;
    const int bid = (xcd < 4) ? (xcd * 290 + ii) : (1160 + (xcd - 4) * 289 + ii);

    const int tid = threadIdx.x;
    const bool isQ = (bid >= 2304);
    int s, tm, tn;
    if (isQ) { s = S_; tm = 0; tn = bid - 2304; }
    else     { s = bid / 36; const int t = bid % 36; tm = t / 12; tn = t % 12; }

    const float* Wsl = isQ ? Wq : (Wv + (size_t)s * H_ * A_);
    const bf16_t* Apanel;
    if (isQ || tm == 0) Apanel = actB;
    else if (tm == 1)   Apanel = actB + TOPIC_N + (size_t)s * B_ * H_;
    else                Apanel = actB + TOPIC_N + IMG_N + (size_t)s * B_ * H_;

    const int wv = tid >> 6, lane = tid & 63;
    const int wr = wv >> 1, wc = wv & 1;          // wave tile 64M x 32N
    const int fr = lane & 15, fg = lane >> 4;

    f32x4 acc[4][2];
    #pragma unroll
    for (int i = 0; i < 4; ++i)
        #pragma unroll
        for (int j = 0; j < 2; ++j)
            acc[i][j] = (f32x4){0.f, 0.f, 0.f, 0.f};

    // stage tile t1 into buffer buf: 4 glds per thread, no register consumers
    auto stage = [&](int t1, int buf) {
        const int k0 = t1 * BK;
        #pragma unroll
        for (int q = 0; q < 2; ++q) {              // W: 16 KB.. 8KB = 8 instrs, 2/wave
            const int cl = (q * 4 + wv) * 64 + lane;   // LDS 16B-chunk 0..511
            const int k = cl >> 4, cc = cl & 15;
            const int cs = (cc - 2 * ((k >> 3) & 3)) & 15;   // inverse rotate
            glds16f(Wsl + (size_t)(k0 + k) * A_ + tn * 64 + cs * 4,
                    &W1[buf][(q * 4 + wv) * 256]);
        }
        #pragma unroll
        for (int q = 0; q < 2; ++q) {              // A: 8 KB = 8 instrs, 2/wave
            const int cl = (q * 4 + wv) * 64 + lane;
            const int row = cl >> 2, c = cl & 3;
            glds16b(Apanel + (size_t)row * H_ + k0 + c * 8,
                    &Al[buf][(q * 4 + wv) * 512]);
        }
    };

    stage(0, 0);

    for (int t = 0; t < NT2; ++t) {
        const int cur = t & 1;
        vm0_bar();                        // tile-t data landed (all waves), join

        // ---- B-frags: read W1[cur] columns (rotate-swizzled: 2-way, free) + cvt
        bf16x8 bfv[2];
        #pragma unroll
        for (int ni = 0; ni < 2; ++ni) {
            const int n = wc * 32 + ni * 16 + fr;
            const int cswz = (((n >> 2) + 2 * fg) & 15) * 4 + (n & 3);
            float bw[8];
            #pragma unroll
            for (int j = 0; j < 8; ++j)
                bw[j] = W1[cur][(fg * 8 + j) * 64 + cswz];
            bf16x8 o;
            #pragma unroll
            for (int j = 0; j < 8; ++j) o[j] = (bf16_t)bw[j];
            bfv[ni] = o;
        }
        // ---- A-frags
        bf16x8 af[4];
        #pragma unroll
        for (int mi = 0; mi < 4; ++mi)
            af[mi] = *reinterpret_cast<const bf16x8*>(
                &Al[cur][(wr * 64 + mi * 16 + fr) * BK + fg * 8]);

        // ---- prefetch t+1 (issued after all LDS reads -> no compiler waits)
        if (t < NT2 - 1) stage(t + 1, cur ^ 1);

        // ---- MFMA (register-only; overlaps the in-flight prefetch)
        #pragma unroll
        for (int mi = 0; mi < 4; ++mi)
            #pragma unroll
            for (int ni = 0; ni < 2; ++ni)
                acc[mi][ni] = __builtin_amdgcn_mfma_f32_16x16x32_bf16(
                    af[mi], bfv[ni], acc[mi][ni], 0, 0, 0);
    }

    // ---- epilogue: C/D map col = lane&15, row = (lane>>4)*4 + j ----
    if (isQ) {
        #pragma unroll
        for (int ni = 0; ni < 2; ++ni) {
            const int n = tn * 64 + wc * 32 + ni * 16 + fr;
            const float bias = bq[n];
            #pragma unroll
            for (int mi = 0; mi < 4; ++mi)
                #pragma unroll
                for (int j = 0; j < 4; ++j) {
                    const int m = wr * 64 + mi * 16 + fg * 4 + j;
                    Qws[(size_t)m * A_ + n] = acc[mi][ni][j] + bias;
                }
        }
    } else {
        const float* bvrow = bv + (size_t)s * A_;
        #pragma unroll
        for (int ni = 0; ni < 2; ++ni) {
            const int n = tn * 64 + wc * 32 + ni * 16 + fr;
            const float bias = bvrow[n];
            #pragma unroll
            for (int mi = 0; mi < 4; ++mi)
                #pragma unroll
                for (int j = 0; j < 4; ++j) {
                    const int b = wr * 64 + mi * 16 + fg * 4 + j;
                    Vws[(((size_t)s * B_ + b) * 3 + tm) * A_ + n] = (bf16_t)(acc[mi][ni][j] + bias);
                }
        }
    }
}

// ---- attention combine: one wave per (s,b) ----
__global__ __launch_bounds__(256)
void mm_attn_kernel(const bf16_t* __restrict__ Vws,
                    const float* __restrict__ Qws,
                    float* __restrict__ out)
{
    const int wave = threadIdx.x >> 6;
    const int lane = threadIdx.x & 63;
    const int p = blockIdx.x * 4 + wave;
    const int s = p >> 7;
    const int b = p & 127;
    const float*  qrow  = Qws + (size_t)b * A_;
    const bf16_t* vbase = Vws + ((size_t)s * B_ + b) * 3 * A_;

    float4 qv[3];
    bf16x4 vv[3][3];
    float p0 = 0.f, p1 = 0.f, p2 = 0.f;
    #pragma unroll
    for (int j = 0; j < 3; ++j) {
        const int a = lane * 4 + j * 256;
        qv[j]    = *reinterpret_cast<const float4*>(qrow + a);
        vv[0][j] = *reinterpret_cast<const bf16x4*>(vbase + 0*A_ + a);
        vv[1][j] = *reinterpret_cast<const bf16x4*>(vbase + 1*A_ + a);
        vv[2][j] = *reinterpret_cast<const bf16x4*>(vbase + 2*A_ + a);
        p0 += qv[j].x*(float)vv[0][j][0] + qv[j].y*(float)vv[0][j][1]
            + qv[j].z*(float)vv[0][j][2] + qv[j].w*(float)vv[0][j][3];
        p1 += qv[j].x*(float)vv[1][j][0] + qv[j].y*(float)vv[1][j][1]
            + qv[j].z*(float)vv[1][j][2] + qv[j].w*(float)vv[1][j][3];
        p2 += qv[j].x*(float)vv[2][j][0] + qv[j].y*(float)vv[2][j][1]
            + qv[j].z*(float)vv[2][j][2] + qv[j].w*(float)vv[2][j][3];
    }
    #pragma unroll
    for (int d = 1; d < 64; d <<= 1) {
        p0 += __shfl_xor(p0, d);
        p1 += __shfl_xor(p1, d);
        p2 += __shfl_xor(p2, d);
    }
    const float norm = 0.03608439182435161f;   // 1/sqrt(768)
    const float s0 = p0 * norm, s1 = p1 * norm, s2 = p2 * norm;
    const float mx = fmaxf(s0, fmaxf(s1, s2));
    const float e0 = expf(s0 - mx), e1 = expf(s1 - mx), e2 = expf(s2 - mx);
    const float inv = 1.f / (e0 + e1 + e2);
    const float a0 = e0 * inv, a1 = e1 * inv, a2 = e2 * inv;

    float* orow = out + ((size_t)s * B_ + b) * A_;
    #pragma unroll
    for (int j = 0; j < 3; ++j) {
        const int a = lane * 4 + j * 256;
        float4 o;
        o.x = a0*(float)vv[0][j][0] + a1*(float)vv[1][j][0] + a2*(float)vv[2][j][0];
        o.y = a0*(float)vv[0][j][1] + a1*(float)vv[1][j][1] + a2*(float)vv[2][j][1];
        o.z = a0*(float)vv[0][j][2] + a1*(float)vv[1][j][2] + a2*(float)vv[2][j][2];
        o.w = a0*(float)vv[0][j][3] + a1*(float)vv[1][j][3] + a2*(float)vv[2][j][3];
        *reinterpret_cast<float4*>(orow + a) = o;
    }
}

// ============================================================================
// FALLBACK PATH (round-1 GEMM, used only if ws_size is too small)
// ============================================================================
#define LDSPAD 40
__global__ __launch_bounds__(256, 2)
void mm_gemm_kernel(const float* __restrict__ topic,
                    const float* __restrict__ image,
                    const float* __restrict__ text,
                    const float* __restrict__ Wq,
                    const float* __restrict__ bq,
                    const float* __restrict__ Wv,
                    const float* __restrict__ bv,
                    bf16_t* __restrict__ Vws,
                    float*  __restrict__ Qws)
{
    __shared__ bf16_t Alds[128][LDSPAD];
    __shared__ bf16_t Blds[128][LDSPAD];

    const int bid = blockIdx.x;
    const int tid = threadIdx.x;
    const bool isQ = (bid >= S_ * 18);
    int s, tm, tn;
    if (isQ) { s = 0; tm = 0; tn = bid - S_ * 18; }
    else     { s = bid / 18; const int t = bid % 18; tm = t / 6; tn = t % 6; }

    const int ar  = tid >> 1;
    const int aks = (tid & 1) * 16;
    const float* arow;
    if (isQ) {
        arow = topic + (size_t)ar * H_;
    } else {
        const int am  = tm * 128 + ar;
        const int sel = am >> 7;
        const int b   = am & 127;
        if (sel == 0)      arow = topic + (size_t)b * H_;
        else if (sel == 1) arow = image + ((size_t)s * B_ + b) * H_;
        else               arow = text  + ((size_t)s * B_ + b) * H_;
    }
    const int arot = (ar >> 3) & 3;

    const int bn  = tid & 127;
    const int bks = (tid >> 7) * 16;
    const float* wbase = isQ ? Wq : (Wv + (size_t)s * H_ * A_);
    const float* bcolp = wbase + (size_t)(tn * 128 + bn);
    const int brot = (bn >> 3) & 3;

    const int wave = tid >> 6;
    const int lane = tid & 63;
    const int wr = wave >> 1;
    const int wc = wave & 1;
    const int fr = lane & 15;
    const int fg = lane >> 4;

    f32x4 acc[4][4];
    #pragma unroll
    for (int i = 0; i < 4; ++i)
        #pragma unroll
        for (int j = 0; j < 4; ++j)
            acc[i][j] = (f32x4){0.f, 0.f, 0.f, 0.f};

    for (int k0 = 0; k0 < H_; k0 += 32) {
        float4 av[4];
        const float4* ap = reinterpret_cast<const float4*>(arow + k0 + aks);
        #pragma unroll
        for (int i = 0; i < 4; ++i) av[i] = ap[i];
        float bvr[16];
        #pragma unroll
        for (int j = 0; j < 16; ++j) bvr[j] = bcolp[(size_t)(k0 + bks + j) * A_];

        __syncthreads();

        #pragma unroll
        for (int i = 0; i < 4; ++i) {
            const int j = (i + arot) & 3;
            bf16x4 c;
            c[0] = (bf16_t)av[j].x; c[1] = (bf16_t)av[j].y;
            c[2] = (bf16_t)av[j].z; c[3] = (bf16_t)av[j].w;
            *reinterpret_cast<bf16x4*>(&Alds[ar][aks + 4*j]) = c;
        }
        #pragma unroll
        for (int i = 0; i < 4; ++i) {
            const int j = (i + brot) & 3;
            bf16x4 c;
            c[0] = (bf16_t)bvr[4*j+0]; c[1] = (bf16_t)bvr[4*j+1];
            c[2] = (bf16_t)bvr[4*j+2]; c[3] = (bf16_t)bvr[4*j+3];
            *reinterpret_cast<bf16x4*>(&Blds[bn][bks + 4*j]) = c;
        }
        __syncthreads();

        bf16x8 afrag[4], bfrag[4];
        #pragma unroll
        for (int mi = 0; mi < 4; ++mi)
            afrag[mi] = *reinterpret_cast<const bf16x8*>(&Alds[wr*64 + mi*16 + fr][fg*8]);
        #pragma unroll
        for (int ni = 0; ni < 4; ++ni)
            bfrag[ni] = *reinterpret_cast<const bf16x8*>(&Blds[wc*64 + ni*16 + fr][fg*8]);
        #pragma unroll
        for (int mi = 0; mi < 4; ++mi)
            #pragma unroll
            for (int ni = 0; ni < 4; ++ni)
                acc[mi][ni] = __builtin_amdgcn_mfma_f32_16x16x32_bf16(
                    afrag[mi], bfrag[ni], acc[mi][ni], 0, 0, 0);
    }

    if (isQ) {
        #pragma unroll
        for (int ni = 0; ni < 4; ++ni) {
            const int n = tn*128 + wc*64 + ni*16 + fr;
            const float bias = bq[n];
            #pragma unroll
            for (int mi = 0; mi < 4; ++mi)
                #pragma unroll
                for (int j = 0; j < 4; ++j) {
                    const int m = wr*64 + mi*16 + fg*4 + j;
                    Qws[(size_t)m * A_ + n] = acc[mi][ni][j] + bias;
                }
        }
    } else {
        const float* bvrow = bv + (size_t)s * A_;
        #pragma unroll
        for (int ni = 0; ni < 4; ++ni) {
            const int n = tn*128 + wc*64 + ni*16 + fr;
            const float bias = bvrow[n];
            #pragma unroll
            for (int mi = 0; mi < 4; ++mi)
                #pragma unroll
                for (int j = 0; j < 4; ++j) {
                    const int b = wr*64 + mi*16 + fg*4 + j;
                    Vws[(((size_t)s * B_ + b) * 3 + tm) * A_ + n] = (bf16_t)(acc[mi][ni][j] + bias);
                }
        }
    }
}

// ============================================================================
extern "C" void kernel_launch(void* const* d_in, const int* in_sizes, int n_in,
                              void* d_out, int out_size, void* d_ws, size_t ws_size,
                              hipStream_t stream)
{
    const float* topic = (const float*)d_in[0];
    const float* image = (const float*)d_in[1];
    const float* text  = (const float*)d_in[2];
    const float* Wq    = (const float*)d_in[3];
    const float* bq    = (const float*)d_in[4];
    const float* Wv    = (const float*)d_in[5];
    const float* bv    = (const float*)d_in[6];
    float* out = (float*)d_out;

    const size_t szAct = (size_t)(TOPIC_N + 2 * IMG_N) * sizeof(bf16_t);  // 25,362,432
    const size_t szV   = (size_t)S_ * B_ * 3 * A_ * sizeof(bf16_t);       // 37,748,736
    const size_t szQ   = (size_t)B_ * A_ * sizeof(float);                 //    393,216
    const size_t need  = szAct + szV + szQ;                               // ~63.5 MB

    if (ws_size >= need) {
        char* w = (char*)d_ws;
        bf16_t* actB = (bf16_t*)w;  w += szAct;
        bf16_t* Vws  = (bf16_t*)w;  w += szV;
        float*  Qws  = (float*) w;

        convert_kernel<<<(TOPIC_N + 2 * IMG_N) / 8 / 256, 256, 0, stream>>>(topic, image, text, actB);
        gemm_direct<<<2316, 256, 0, stream>>>(Wv, Wq, actB, bq, bv, Vws, Qws);
        mm_attn_kernel<<<S_ * B_ / 4, 256, 0, stream>>>(Vws, Qws, out);
    } else {
        bf16_t* Vws = (bf16_t*)d_ws;
        float*  Qws = (float*)((char*)d_ws + szV);
        mm_gemm_kernel<<<S_ * 18 + 6, 256, 0, stream>>>(topic, image, text, Wq, bq, Wv, bv, Vws, Qws);
        mm_attn_kernel<<<S_ * B_ / 4, 256, 0, stream>>>(Vws, Qws, out);
    }
}